// Round 1
// baseline (310.660 us; speedup 1.0000x reference)
//
#include <hip/hip_runtime.h>

// MADE flow: u = (x - m)*exp(-a), logdet = -sum(a)
// B=524288, NI=32, H=128, NC=64.
// Strategy: fully fused 3-layer MFMA (f16 in, fp32 acc), activations kept
// TRANSPOSED (hidden x batch) so MFMA C/D layout == next layer's B-operand
// layout (row=(l>>4)*4+r  <->  k=(l>>4)*4+j, col==n==l&15): register-direct
// chaining, no LDS, no barriers. Weights are pre-masked/f16/fragment-ordered
// into d_ws by a tiny prep kernel; main kernel loads them as coalesced
// 8B/lane dwordx2 (72KB total, L1/L2 resident).

#define B_ROWS 524288
#define NI 32
#define HD 128
#define NC 64

#define L2_BASE 48    // L1 frags: 8 jt * 6 kt
#define L3_BASE 112   // L2 frags: 8 jt * 8 kt
#define N_FRAGS 144   // L3 frags: 4 jt * 8 kt

typedef _Float16 half4 __attribute__((ext_vector_type(4)));
typedef float f32x4 __attribute__((ext_vector_type(4)));

__device__ inline half4 cvt4(f32x4 v) {
  half4 h;
  h[0] = (_Float16)v[0]; h[1] = (_Float16)v[1];
  h[2] = (_Float16)v[2]; h[3] = (_Float16)v[3];
  return h;
}

// ---------------- prep: masked f16 weights in MFMA-A fragment order ----------
// Fragment (frag, lane) holds A[m][k]: m = jt*16 + (lane&15),
// k = kt*16 + (lane>>4)*4 + i  (i=0..3). Stored at wf[frag*256 + lane*4 + i].
__global__ void prep_weights(const float* __restrict__ W1, const float* __restrict__ Wc,
                             const float* __restrict__ W2, const float* __restrict__ W3,
                             _Float16* __restrict__ wf) {
  int tid = blockIdx.x * blockDim.x + threadIdx.x;
  if (tid >= N_FRAGS * 64) return;
  int frag = tid >> 6;
  int lane = tid & 63;
  int q = lane >> 4, c = lane & 15;
  int L, jt, kt;
  if (frag < L2_BASE)      { L = 0; jt = frag / 6;             kt = frag % 6; }
  else if (frag < L3_BASE) { L = 1; jt = (frag - L2_BASE) >> 3; kt = (frag - L2_BASE) & 7; }
  else                     { L = 2; jt = (frag - L3_BASE) >> 3; kt = (frag - L3_BASE) & 7; }
  int j = jt * 16 + c;  // output unit (row of W)
  half4 v;
#pragma unroll
  for (int i = 0; i < 4; ++i) {
    int k = kt * 16 + q * 4 + i;
    float w;
    if (L == 0) {
      // layer1 K-dim is [x(32) | cond(64)]; mask m1 = (j%31 >= k), Wc unmasked
      if (k < NI) w = ((j % 31) >= k) ? W1[j * NI + k] : 0.f;
      else        w = Wc[j * NC + (k - NI)];
    } else if (L == 1) {
      w = ((j % 31) >= (k % 31)) ? W2[j * HD + k] : 0.f;          // m2
    } else {
      w = (((j % 32) - 1) >= (k % 31)) ? W3[j * HD + k] : 0.f;    // m3
    }
    v[i] = (_Float16)w;
  }
  *(half4*)(wf + (size_t)tid * 4) = v;
}

// ---------------- fused main kernel ----------------
// 4 waves/block, each wave owns 64 batch rows (nt = 4 tiles of 16).
// Grid = B/(4*64) = 2048 blocks, exact fit.
__global__ __launch_bounds__(256, 2) void made_fused(
    const float* __restrict__ x, const float* __restrict__ cond,
    const float* __restrict__ b1, const float* __restrict__ b2,
    const float* __restrict__ b3, const _Float16* __restrict__ wf,
    float* __restrict__ out) {
  const int lane = threadIdx.x & 63;
  const int wid  = threadIdx.x >> 6;
  const int q = lane >> 4, c = lane & 15;
  const long rowbase = ((long)blockIdx.x * 4 + wid) * 64;

  // ---- L1 B-fragments (activations^T): bf[kt][nt], kt over [x|cond] K=96
  half4 bf[6][4];
#pragma unroll
  for (int nt = 0; nt < 4; ++nt) {
    const float* xr = x    + (rowbase + nt * 16 + c) * NI;
    const float* cr = cond + (rowbase + nt * 16 + c) * NC;
    bf[0][nt] = cvt4(*(const f32x4*)(xr + q * 4));
    bf[1][nt] = cvt4(*(const f32x4*)(xr + 16 + q * 4));
    bf[2][nt] = cvt4(*(const f32x4*)(cr + q * 4));
    bf[3][nt] = cvt4(*(const f32x4*)(cr + 16 + q * 4));
    bf[4][nt] = cvt4(*(const f32x4*)(cr + 32 + q * 4));
    bf[5][nt] = cvt4(*(const f32x4*)(cr + 48 + q * 4));
  }

  // ---- layer 1: D1[j][b] = W1c @ [x|cond]^T + b1, relu  (8 jt x 6 kt)
  f32x4 acc[8][4];
#pragma unroll
  for (int jt = 0; jt < 8; ++jt) {
    f32x4 bv = *(const f32x4*)(b1 + jt * 16 + q * 4);  // bias of row jt*16+q*4+r
#pragma unroll
    for (int nt = 0; nt < 4; ++nt) acc[jt][nt] = bv;
  }
#pragma unroll
  for (int jt = 0; jt < 8; ++jt) {
#pragma unroll
    for (int kt = 0; kt < 6; ++kt) {
      half4 a = *(const half4*)(wf + (((jt * 6 + kt) * 64 + lane) << 2));
#pragma unroll
      for (int nt = 0; nt < 4; ++nt)
        acc[jt][nt] = __builtin_amdgcn_mfma_f32_16x16x16f16(a, bf[kt][nt], acc[jt][nt], 0, 0, 0);
    }
  }
  half4 h1[8][4];  // == B-fragments of layer 2, register-direct
#pragma unroll
  for (int jt = 0; jt < 8; ++jt)
#pragma unroll
    for (int nt = 0; nt < 4; ++nt) {
      f32x4 v = acc[jt][nt];
      v[0] = fmaxf(v[0], 0.f); v[1] = fmaxf(v[1], 0.f);
      v[2] = fmaxf(v[2], 0.f); v[3] = fmaxf(v[3], 0.f);
      h1[jt][nt] = cvt4(v);
    }

  // ---- layer 2 (8 jt x 8 kt)
#pragma unroll
  for (int jt = 0; jt < 8; ++jt) {
    f32x4 bv = *(const f32x4*)(b2 + jt * 16 + q * 4);
#pragma unroll
    for (int nt = 0; nt < 4; ++nt) acc[jt][nt] = bv;
  }
#pragma unroll
  for (int jt = 0; jt < 8; ++jt) {
#pragma unroll
    for (int kt = 0; kt < 8; ++kt) {
      half4 a = *(const half4*)(wf + (((L2_BASE + jt * 8 + kt) * 64 + lane) << 2));
#pragma unroll
      for (int nt = 0; nt < 4; ++nt)
        acc[jt][nt] = __builtin_amdgcn_mfma_f32_16x16x16f16(a, h1[kt][nt], acc[jt][nt], 0, 0, 0);
    }
  }
  half4 h2[8][4];
#pragma unroll
  for (int jt = 0; jt < 8; ++jt)
#pragma unroll
    for (int nt = 0; nt < 4; ++nt) {
      f32x4 v = acc[jt][nt];
      v[0] = fmaxf(v[0], 0.f); v[1] = fmaxf(v[1], 0.f);
      v[2] = fmaxf(v[2], 0.f); v[3] = fmaxf(v[3], 0.f);
      h2[jt][nt] = cvt4(v);
    }

  // ---- layer 3 (4 jt x 8 kt): o[0:32]=m_, o[32:64]=a
  f32x4 acc3[4][4];
#pragma unroll
  for (int jt = 0; jt < 4; ++jt) {
    f32x4 bv = *(const f32x4*)(b3 + jt * 16 + q * 4);
#pragma unroll
    for (int nt = 0; nt < 4; ++nt) acc3[jt][nt] = bv;
  }
#pragma unroll
  for (int jt = 0; jt < 4; ++jt) {
#pragma unroll
    for (int kt = 0; kt < 8; ++kt) {
      half4 a = *(const half4*)(wf + (((L3_BASE + jt * 8 + kt) * 64 + lane) << 2));
#pragma unroll
      for (int nt = 0; nt < 4; ++nt)
        acc3[jt][nt] = __builtin_amdgcn_mfma_f32_16x16x16f16(a, h2[kt][nt], acc3[jt][nt], 0, 0, 0);
    }
  }

  // ---- epilogue: lane owns batch row m = rowbase+nt*16+c, output idx
  // i = q*4+r (jt0/jt2) and 16+q*4+r (jt1/jt3); m_ and a pair up in-lane.
#pragma unroll
  for (int nt = 0; nt < 4; ++nt) {
    long m = rowbase + nt * 16 + c;
    const float* xr = x + m * NI;
    f32x4 xa = *(const f32x4*)(xr + q * 4);
    f32x4 xb = *(const f32x4*)(xr + 16 + q * 4);
    f32x4 mva = acc3[0][nt], mvb = acc3[1][nt];
    f32x4 ava = acc3[2][nt], avb = acc3[3][nt];
    f32x4 ua, ub;
    float s = 0.f;
#pragma unroll
    for (int i = 0; i < 4; ++i) {
      float aa = fminf(fmaxf(ava[i], -5.f), 5.f);
      float ab = fminf(fmaxf(avb[i], -5.f), 5.f);
      ua[i] = (xa[i] - mva[i]) * __expf(-aa);
      ub[i] = (xb[i] - mvb[i]) * __expf(-ab);
      s += aa + ab;
    }
    *(f32x4*)(out + m * NI + q * 4) = ua;
    *(f32x4*)(out + m * NI + 16 + q * 4) = ub;
    s += __shfl_xor(s, 16);
    s += __shfl_xor(s, 32);
    if (q == 0) out[(long)B_ROWS * NI + m] = -s;  // logdet
  }
}

extern "C" void kernel_launch(void* const* d_in, const int* in_sizes, int n_in,
                              void* d_out, int out_size, void* d_ws, size_t ws_size,
                              hipStream_t stream) {
  const float* x    = (const float*)d_in[0];
  const float* cond = (const float*)d_in[1];
  const float* W1   = (const float*)d_in[2];
  const float* b1   = (const float*)d_in[3];
  const float* Wc   = (const float*)d_in[4];
  const float* W2   = (const float*)d_in[5];
  const float* b2   = (const float*)d_in[6];
  const float* W3   = (const float*)d_in[7];
  const float* b3   = (const float*)d_in[8];
  _Float16* wf = (_Float16*)d_ws;  // 144 frags * 256 halfs = 72 KB

  prep_weights<<<(N_FRAGS * 64 + 255) / 256, 256, 0, stream>>>(W1, Wc, W2, W3, wf);
  made_fused<<<B_ROWS / 256, 256, 0, stream>>>(x, cond, b1, b2, b3, wf, (float*)d_out);
}

// Round 2
// 306.791 us; speedup vs baseline: 1.0126x; 1.0126x over previous
//
#include <hip/hip_runtime.h>

// MADE flow: u = (x - m)*exp(-a), logdet = -sum(a)
// B=524288, NI=32, H=128, NC=64.
// R2: keep register-direct K=16 MFMA chaining (C/D layout == next B layout);
// fix latency-boundness: L2/L3 weights staged in LDS (48KB, conflict-free
// ds_read_b64), nt=4->2 to cut regs (target 3 waves/SIMD), block=256,
// launch_bounds(256,3), grid=4096. L1 weights stay global (overlap HBM
// latency of x/cond loads).

#define B_ROWS 524288
#define NI 32
#define HD 128
#define NC 64

#define L2_BASE 48    // L1 frags: 8 jt * 6 kt
#define L3_BASE 112   // L2 frags: 8 jt * 8 kt
#define N_FRAGS 144   // L3 frags: 4 jt * 8 kt

typedef _Float16 half4 __attribute__((ext_vector_type(4)));
typedef float f32x4 __attribute__((ext_vector_type(4)));

__device__ inline half4 cvt4(f32x4 v) {
  half4 h;
  h[0] = (_Float16)v[0]; h[1] = (_Float16)v[1];
  h[2] = (_Float16)v[2]; h[3] = (_Float16)v[3];
  return h;
}

// ---------------- prep: masked f16 weights in MFMA-A fragment order ----------
// Fragment (frag, lane) holds A[m][k]: m = jt*16 + (lane&15),
// k = kt*16 + (lane>>4)*4 + i  (i=0..3). Stored at wf[frag*256 + lane*4 + i].
__global__ void prep_weights(const float* __restrict__ W1, const float* __restrict__ Wc,
                             const float* __restrict__ W2, const float* __restrict__ W3,
                             _Float16* __restrict__ wf) {
  int tid = blockIdx.x * blockDim.x + threadIdx.x;
  if (tid >= N_FRAGS * 64) return;
  int frag = tid >> 6;
  int lane = tid & 63;
  int q = lane >> 4, c = lane & 15;
  int L, jt, kt;
  if (frag < L2_BASE)      { L = 0; jt = frag / 6;             kt = frag % 6; }
  else if (frag < L3_BASE) { L = 1; jt = (frag - L2_BASE) >> 3; kt = (frag - L2_BASE) & 7; }
  else                     { L = 2; jt = (frag - L3_BASE) >> 3; kt = (frag - L3_BASE) & 7; }
  int j = jt * 16 + c;  // output unit (row of W)
  half4 v;
#pragma unroll
  for (int i = 0; i < 4; ++i) {
    int k = kt * 16 + q * 4 + i;
    float w;
    if (L == 0) {
      // layer1 K-dim is [x(32) | cond(64)]; mask m1 = (j%31 >= k), Wc unmasked
      if (k < NI) w = ((j % 31) >= k) ? W1[j * NI + k] : 0.f;
      else        w = Wc[j * NC + (k - NI)];
    } else if (L == 1) {
      w = ((j % 31) >= (k % 31)) ? W2[j * HD + k] : 0.f;          // m2
    } else {
      w = (((j % 32) - 1) >= (k % 31)) ? W3[j * HD + k] : 0.f;    // m3
    }
    v[i] = (_Float16)w;
  }
  *(half4*)(wf + (size_t)tid * 4) = v;
}

// ---------------- fused main kernel ----------------
// 4 waves/block, each wave owns 32 batch rows (nt = 2 tiles of 16).
// Grid = B/(4*32) = 4096 blocks.
__global__ __launch_bounds__(256, 3) void made_fused(
    const float* __restrict__ x, const float* __restrict__ cond,
    const float* __restrict__ b1, const float* __restrict__ b2,
    const float* __restrict__ b3, const _Float16* __restrict__ wf,
    float* __restrict__ out) {
  // L2+L3 weight fragments staged in LDS: frags 48..143 -> 96*512B = 48KB
  __shared__ _Float16 wlds[96 * 256];

  const int tid  = threadIdx.x;
  const int lane = tid & 63;
  const int wid  = tid >> 6;
  const int q = lane >> 4, c = lane & 15;
  const long rowbase = ((long)blockIdx.x * 4 + wid) * 32;

  // ---- stage L2/L3 weights into LDS (3072 f32x4, 12 per thread) ----
  {
    const f32x4* src = (const f32x4*)(wf + L2_BASE * 256);
    f32x4* dst = (f32x4*)wlds;
#pragma unroll
    for (int k = 0; k < 12; ++k) dst[tid + k * 256] = src[tid + k * 256];
  }

  // ---- L1 B-fragments (activations^T): bf[kt][nt], kt over [x|cond] K=96
  half4 bf[6][2];
#pragma unroll
  for (int nt = 0; nt < 2; ++nt) {
    const float* xr = x    + (rowbase + nt * 16 + c) * NI;
    const float* cr = cond + (rowbase + nt * 16 + c) * NC;
    bf[0][nt] = cvt4(*(const f32x4*)(xr + q * 4));
    bf[1][nt] = cvt4(*(const f32x4*)(xr + 16 + q * 4));
    bf[2][nt] = cvt4(*(const f32x4*)(cr + q * 4));
    bf[3][nt] = cvt4(*(const f32x4*)(cr + 16 + q * 4));
    bf[4][nt] = cvt4(*(const f32x4*)(cr + 32 + q * 4));
    bf[5][nt] = cvt4(*(const f32x4*)(cr + 48 + q * 4));
  }

  // ---- layer 1: D1[j][b] = W1c @ [x|cond]^T + b1, relu  (8 jt x 6 kt)
  // weights from GLOBAL (L2-resident, overlaps x/cond HBM latency)
  f32x4 acc[8][2];
#pragma unroll
  for (int jt = 0; jt < 8; ++jt) {
    f32x4 bv = *(const f32x4*)(b1 + jt * 16 + q * 4);
#pragma unroll
    for (int nt = 0; nt < 2; ++nt) acc[jt][nt] = bv;
  }
#pragma unroll
  for (int jt = 0; jt < 8; ++jt) {
#pragma unroll
    for (int kt = 0; kt < 6; ++kt) {
      half4 a = *(const half4*)(wf + (((jt * 6 + kt) * 64 + lane) << 2));
#pragma unroll
      for (int nt = 0; nt < 2; ++nt)
        acc[jt][nt] = __builtin_amdgcn_mfma_f32_16x16x16f16(a, bf[kt][nt], acc[jt][nt], 0, 0, 0);
    }
  }
  half4 h1[8][2];  // == B-fragments of layer 2, register-direct
#pragma unroll
  for (int jt = 0; jt < 8; ++jt)
#pragma unroll
    for (int nt = 0; nt < 2; ++nt) {
      f32x4 v = acc[jt][nt];
      v[0] = fmaxf(v[0], 0.f); v[1] = fmaxf(v[1], 0.f);
      v[2] = fmaxf(v[2], 0.f); v[3] = fmaxf(v[3], 0.f);
      h1[jt][nt] = cvt4(v);
    }

  __syncthreads();  // LDS weights ready; all later weight reads hit LDS

  // ---- layer 2 (8 jt x 8 kt), weights from LDS
#pragma unroll
  for (int jt = 0; jt < 8; ++jt) {
    f32x4 bv = *(const f32x4*)(b2 + jt * 16 + q * 4);
#pragma unroll
    for (int nt = 0; nt < 2; ++nt) acc[jt][nt] = bv;
  }
#pragma unroll
  for (int jt = 0; jt < 8; ++jt) {
#pragma unroll
    for (int kt = 0; kt < 8; ++kt) {
      half4 a = *(const half4*)(wlds + (((jt * 8 + kt) * 64 + lane) << 2));
#pragma unroll
      for (int nt = 0; nt < 2; ++nt)
        acc[jt][nt] = __builtin_amdgcn_mfma_f32_16x16x16f16(a, h1[kt][nt], acc[jt][nt], 0, 0, 0);
    }
  }
  half4 h2[8][2];
#pragma unroll
  for (int jt = 0; jt < 8; ++jt)
#pragma unroll
    for (int nt = 0; nt < 2; ++nt) {
      f32x4 v = acc[jt][nt];
      v[0] = fmaxf(v[0], 0.f); v[1] = fmaxf(v[1], 0.f);
      v[2] = fmaxf(v[2], 0.f); v[3] = fmaxf(v[3], 0.f);
      h2[jt][nt] = cvt4(v);
    }

  // ---- layer 3 (4 jt x 8 kt), weights from LDS: o[0:32]=m_, o[32:64]=a
  f32x4 acc3[4][2];
#pragma unroll
  for (int jt = 0; jt < 4; ++jt) {
    f32x4 bv = *(const f32x4*)(b3 + jt * 16 + q * 4);
#pragma unroll
    for (int nt = 0; nt < 2; ++nt) acc3[jt][nt] = bv;
  }
#pragma unroll
  for (int jt = 0; jt < 4; ++jt) {
#pragma unroll
    for (int kt = 0; kt < 8; ++kt) {
      half4 a = *(const half4*)(wlds + (((64 + jt * 8 + kt) * 64 + lane) << 2));
#pragma unroll
      for (int nt = 0; nt < 2; ++nt)
        acc3[jt][nt] = __builtin_amdgcn_mfma_f32_16x16x16f16(a, h2[kt][nt], acc3[jt][nt], 0, 0, 0);
    }
  }

  // ---- epilogue: lane owns batch row m = rowbase+nt*16+c, output idx
  // i = q*4+r (jt0/jt2) and 16+q*4+r (jt1/jt3); m_ and a pair up in-lane.
#pragma unroll
  for (int nt = 0; nt < 2; ++nt) {
    long m = rowbase + nt * 16 + c;
    const float* xr = x + m * NI;   // L2-hit re-read (saves 16 VGPRs held live)
    f32x4 xa = *(const f32x4*)(xr + q * 4);
    f32x4 xb = *(const f32x4*)(xr + 16 + q * 4);
    f32x4 mva = acc3[0][nt], mvb = acc3[1][nt];
    f32x4 ava = acc3[2][nt], avb = acc3[3][nt];
    f32x4 ua, ub;
    float s = 0.f;
#pragma unroll
    for (int i = 0; i < 4; ++i) {
      float aa = fminf(fmaxf(ava[i], -5.f), 5.f);
      float ab = fminf(fmaxf(avb[i], -5.f), 5.f);
      ua[i] = (xa[i] - mva[i]) * __expf(-aa);
      ub[i] = (xb[i] - mvb[i]) * __expf(-ab);
      s += aa + ab;
    }
    *(f32x4*)(out + m * NI + q * 4) = ua;
    *(f32x4*)(out + m * NI + 16 + q * 4) = ub;
    s += __shfl_xor(s, 16);
    s += __shfl_xor(s, 32);
    if (q == 0) out[(long)B_ROWS * NI + m] = -s;  // logdet
  }
}

extern "C" void kernel_launch(void* const* d_in, const int* in_sizes, int n_in,
                              void* d_out, int out_size, void* d_ws, size_t ws_size,
                              hipStream_t stream) {
  const float* x    = (const float*)d_in[0];
  const float* cond = (const float*)d_in[1];
  const float* W1   = (const float*)d_in[2];
  const float* b1   = (const float*)d_in[3];
  const float* Wc   = (const float*)d_in[4];
  const float* W2   = (const float*)d_in[5];
  const float* b2   = (const float*)d_in[6];
  const float* W3   = (const float*)d_in[7];
  const float* b3   = (const float*)d_in[8];
  _Float16* wf = (_Float16*)d_ws;  // 144 frags * 256 halfs = 72 KB

  prep_weights<<<(N_FRAGS * 64 + 255) / 256, 256, 0, stream>>>(W1, Wc, W2, W3, wf);
  made_fused<<<B_ROWS / 128, 256, 0, stream>>>(x, cond, b1, b2, b3, wf, (float*)d_out);
}